// Round 2
// baseline (1930.920 us; speedup 1.0000x reference)
//
#include <hip/hip_runtime.h>
#include <hip/hip_bf16.h>
#include <stdint.h>

typedef __bf16 bf16_t;
typedef __bf16 bf16x8 __attribute__((ext_vector_type(8)));
typedef __bf16 bf16x4_t __attribute__((ext_vector_type(4)));
typedef float f32x4 __attribute__((ext_vector_type(4)));

#define T_STEPS 512
#define B_SZ 64
#define I_SZ 512
#define H_SZ 512
#define NB 4            // batch groups (16 rows each)
#define BS 16
#define NC 32           // column-group WGs per batch group (16 h-cols each)
#define CS 16
#define CNT_TARGET 128  // 4 waves x 32 WGs signal per (bg, t)

// ws layout (bytes)
#define XBF_OFF   0ull                     // 32 MB: x bf16, consumer-fragment order
#define WBF_OFF   33554432ull              // 4 MB: W_all bf16 row-major [2048][1024]
#define BALL_OFF  (WBF_OFF + 4194304ull)   // 8 KB: b_all f32
#define HEXP_OFF  (BALL_OFF + 8192ull)     // 256 KB: packed h exchange
// HEXP: [par 2][bg 4][wh 2][kt 8][lane 64][j 8] dwords, each = (tag<<16)|bf16(h)
#define FLGC_OFF  (HEXP_OFF + 262144ull)   // 8 KB: per-(bg,t) wave-completion counters

__device__ __forceinline__ float sigmoid_fast(float x) {
  return 1.f / (1.f + __expf(-x));
}
__device__ __forceinline__ float tanh_fast(float x) {
  float xc = fminf(fmaxf(x, -10.f), 10.f);
  float e = __expf(2.f * xc);
  return (e - 1.f) / (e + 1.f);
}

// ---- device-coherent (L1+L2 bypass -> Infinity Cache) accessors (R2-proven instrs) ----
__device__ __forceinline__ uint4 load_b128_cc(const void* addr) {
  uint4 v;
  asm volatile("global_load_dwordx4 %0, %1, off sc0 sc1"
               : "=v"(v) : "v"(addr) : "memory");
  return v;
}
__device__ __forceinline__ void store_b32_cc(void* addr, uint32_t v) {
  asm volatile("global_store_dword %0, %1, off sc0 sc1"
               :: "v"(addr), "v"(v) : "memory");
}
__device__ __forceinline__ void wait_vm0() {
  asm volatile("s_waitcnt vmcnt(0)" ::: "memory");
}

// ---------- prep: cast x to bf16 in consumer-fragment order ----------
// chunk c (8 bf16): c = t*4096 + bg*1024 + w*512 + kt*64 + lane
// source: row = bg*16 + (lane&15), col = w*256 + kt*32 + (lane>>4)*8
__global__ void prep_x(const float* __restrict__ x, bf16_t* __restrict__ xbf) {
  const int nch = (T_STEPS * B_SZ * I_SZ) / 8;   // 2,097,152
  int c = blockIdx.x * blockDim.x + threadIdx.x;
  int stride = gridDim.x * blockDim.x;
  for (; c < nch; c += stride) {
    int lane = c & 63;
    int kt = (c >> 6) & 7;
    int w  = (c >> 9) & 1;
    int bg = (c >> 10) & 3;
    int t  = c >> 12;
    int r = lane & 15, quad = lane >> 4;
    const float* src = x + ((size_t)t * B_SZ + bg * BS + r) * I_SZ + w * 256 + kt * 32 + quad * 8;
    float4 lo = *(const float4*)src;
    float4 hi = *(const float4*)(src + 4);
    bf16x8 o = { (bf16_t)lo.x, (bf16_t)lo.y, (bf16_t)lo.z, (bf16_t)lo.w,
                 (bf16_t)hi.x, (bf16_t)hi.y, (bf16_t)hi.z, (bf16_t)hi.w };
    *(bf16x8*)(xbf + (size_t)c * 8) = o;
  }
}

// ---------- prep: W_all bf16, b_all f32, zero packed h-exchange + counters ----------
__global__ void prep_rest(const float* __restrict__ wf, const float* __restrict__ wi,
                          const float* __restrict__ wgm, const float* __restrict__ wo,
                          const float* __restrict__ bfv, const float* __restrict__ biv,
                          const float* __restrict__ bgv, const float* __restrict__ bov,
                          bf16_t* __restrict__ wbf, float* __restrict__ ball,
                          uint32_t* __restrict__ hexp, uint32_t* __restrict__ flgc) {
  int gtid = blockIdx.x * blockDim.x + threadIdx.x;
  int stride = gridDim.x * blockDim.x;
  const int WCH = (2048 * 1024) / 4;  // 524288 float4 chunks
  for (int i = gtid; i < WCH; i += stride) {
    int r = i >> 8;               // W_all row (0..2047)
    int c = (i & 255) << 2;       // col base
    int g = r >> 9, sr = r & 511;
    const float* src = (g == 0) ? wf : (g == 1) ? wi : (g == 2) ? wgm : wo;
    float4 v = *(const float4*)(src + (size_t)sr * 1024 + c);
    bf16x4_t o = { (bf16_t)v.x, (bf16_t)v.y, (bf16_t)v.z, (bf16_t)v.w };
    *(bf16x4_t*)(wbf + (size_t)r * 1024 + c) = o;
  }
  for (int i = gtid; i < 2048; i += stride) {
    int g = i >> 9;
    const float* src = (g == 0) ? bfv : (g == 1) ? biv : (g == 2) ? bgv : bov;
    ball[i] = src[i & 511];
  }
  for (int i = gtid; i < 65536; i += stride) hexp[i] = 0;       // tag 0 == "h(-1)=0 ready"
  for (int i = gtid; i < NB * T_STEPS; i += stride) flgc[i] = 0;
}

// ---------- main recurrent kernel ----------
// 128 WGs; 4-way symmetric K-split (each wave: 128 x-dims + 128 h-dims);
// counter-hint sync (broadcast dword spin) + tag-validated bulk load.
__global__ __launch_bounds__(256, 1) void qlstm_main(
    const bf16_t* __restrict__ xbf, const bf16_t* __restrict__ wbf,
    const float* __restrict__ ball, uint32_t* __restrict__ hexp,
    uint32_t* __restrict__ flgc, float* __restrict__ out) {
  const int wg = blockIdx.x;
  const int bg = wg >> 5;      // batch group 0..3
  const int ic = wg & 31;      // column group 0..31
  const int tid = threadIdx.x;
  const int wave = tid >> 6;   // K-quarter owner (x[128w..] and h[128w..])
  const int lane = tid & 63;
  const int l15 = lane & 15;
  const int quad = lane >> 4;
  const int kq = wave * 4;     // base K-tile (of 32) within each 512-half

  // partial-sum exchange: [par][wave][row 16][col 64(+4 pad)] (col = l15*4 + gate)
  __shared__ __align__(16) float Gp[2][4][16][68];

  // Register-resident B fragments: W_all row = g*512 + ic*16 + l15
  // j<4: x quarter, col = (kq+j)*32 + quad*8 ; j>=4: h quarter, col = 512 + (kq+j-4)*32 + quad*8
  bf16x8 wfr[4][8];
#pragma unroll
  for (int g = 0; g < 4; ++g) {
    const bf16_t* wp = wbf + ((size_t)(g * 512 + ic * CS + l15)) * 1024 + quad * 8;
#pragma unroll
    for (int j = 0; j < 4; ++j) {
      wfr[g][j]     = *(const bf16x8*)(wp + (kq + j) * 32);
      wfr[g][4 + j] = *(const bf16x8*)(wp + 512 + (kq + j) * 32);
    }
  }

  // shared per-j offset (x: bf16 elems; hexp: dwords): both are [wh][kt][lane][8]
  int off[4];
#pragma unroll
  for (int j = 0; j < 4; ++j)
    off[j] = (((kq + j) >> 3) << 12) + (((kq + j) & 7) << 9) + lane * 8;

  const int erow = tid >> 4;
  const int ecol = tid & 15;
  const float bias_f = ball[0 * 512 + ic * CS + ecol];
  const float bias_i = ball[1 * 512 + ic * CS + ecol];
  const float bias_g = ball[2 * 512 + ic * CS + ecol];
  const float bias_o = ball[3 * 512 + ic * CS + ecol];

  const int brow = bg * BS + erow;
  const int hcol = ic * CS + ecol;

  // producer dest: fragment position of (erow, hcol) in consumer layout (unchanged)
  const int wh = hcol >> 8;
  const int kp = hcol & 255;
  const int pof = wh * 4096 + ((kp >> 5) << 9) + ((((kp >> 3) & 3) * 16 + erow) << 3) + (kp & 7);

  float c_state = 0.f, h = 0.f;
  const size_t out_hx = (size_t)T_STEPS * B_SZ * H_SZ;

  const bf16_t* xwb = xbf + ((size_t)bg << 13);   // + t<<15 + off[j]

#pragma unroll 1
  for (int t = 0; t < T_STEPS; ++t) {
    const int par = t & 1;

    // ---- issue first readiness probe early (latency hides under x phase)
    const uint32_t* cp = flgc + bg * T_STEPS + (t > 0 ? t - 1 : 0);
    uint32_t cval = CNT_TARGET;
    if (t > 0)
      cval = __hip_atomic_load(cp, __ATOMIC_RELAXED, __HIP_MEMORY_SCOPE_AGENT);

    // ---- x K-quarter: fragment loads + MFMA (off critical path)
    f32x4 x0 = {0, 0, 0, 0}, x1 = {0, 0, 0, 0}, x2 = {0, 0, 0, 0}, x3 = {0, 0, 0, 0};
    {
      const bf16_t* xp = xwb + ((size_t)t << 15);
      bf16x8 fx0 = *(const bf16x8*)(xp + off[0]);
      bf16x8 fx1 = *(const bf16x8*)(xp + off[1]);
      bf16x8 fx2 = *(const bf16x8*)(xp + off[2]);
      bf16x8 fx3 = *(const bf16x8*)(xp + off[3]);
      x0 = __builtin_amdgcn_mfma_f32_16x16x32_bf16(fx0, wfr[0][0], x0, 0, 0, 0);
      x1 = __builtin_amdgcn_mfma_f32_16x16x32_bf16(fx0, wfr[1][0], x1, 0, 0, 0);
      x2 = __builtin_amdgcn_mfma_f32_16x16x32_bf16(fx0, wfr[2][0], x2, 0, 0, 0);
      x3 = __builtin_amdgcn_mfma_f32_16x16x32_bf16(fx0, wfr[3][0], x3, 0, 0, 0);
      x0 = __builtin_amdgcn_mfma_f32_16x16x32_bf16(fx1, wfr[0][1], x0, 0, 0, 0);
      x1 = __builtin_amdgcn_mfma_f32_16x16x32_bf16(fx1, wfr[1][1], x1, 0, 0, 0);
      x2 = __builtin_amdgcn_mfma_f32_16x16x32_bf16(fx1, wfr[2][1], x2, 0, 0, 0);
      x3 = __builtin_amdgcn_mfma_f32_16x16x32_bf16(fx1, wfr[3][1], x3, 0, 0, 0);
      x0 = __builtin_amdgcn_mfma_f32_16x16x32_bf16(fx2, wfr[0][2], x0, 0, 0, 0);
      x1 = __builtin_amdgcn_mfma_f32_16x16x32_bf16(fx2, wfr[1][2], x1, 0, 0, 0);
      x2 = __builtin_amdgcn_mfma_f32_16x16x32_bf16(fx2, wfr[2][2], x2, 0, 0, 0);
      x3 = __builtin_amdgcn_mfma_f32_16x16x32_bf16(fx2, wfr[3][2], x3, 0, 0, 0);
      x0 = __builtin_amdgcn_mfma_f32_16x16x32_bf16(fx3, wfr[0][3], x0, 0, 0, 0);
      x1 = __builtin_amdgcn_mfma_f32_16x16x32_bf16(fx3, wfr[1][3], x1, 0, 0, 0);
      x2 = __builtin_amdgcn_mfma_f32_16x16x32_bf16(fx3, wfr[2][3], x2, 0, 0, 0);
      x3 = __builtin_amdgcn_mfma_f32_16x16x32_bf16(fx3, wfr[3][3], x3, 0, 0, 0);
    }

    // ---- spin on the broadcast counter (single dword, uncontended)
    while (cval < CNT_TARGET)
      cval = __hip_atomic_load(cp, __ATOMIC_RELAXED, __HIP_MEMORY_SCOPE_AGENT);

    // ---- bulk load h quarter once; MFMA speculatively; tag-validate under MFMA latency
    const uint32_t* hb = hexp + ((size_t)(((par ^ 1) * 4 + bg)) << 13);
    const uint32_t pat = (uint32_t)t << 16;
    f32x4 a0, a1, a2, a3;
    uint32_t bad;
    do {
      uint4 v[8];
#pragma unroll
      for (int j = 0; j < 4; ++j) {
        v[2 * j]     = load_b128_cc(hb + off[j]);
        v[2 * j + 1] = load_b128_cc(hb + off[j] + 4);
      }
      wait_vm0();
      a0 = x0; a1 = x1; a2 = x2; a3 = x3;
#pragma unroll
      for (int j = 0; j < 4; ++j) {
        uint4 a = v[2 * j], b = v[2 * j + 1];
        union { uint32_t u[4]; bf16x8 fv; } cv;
        cv.u[0] = (a.x & 0xffffu) | (a.y << 16);
        cv.u[1] = (a.z & 0xffffu) | (a.w << 16);
        cv.u[2] = (b.x & 0xffffu) | (b.y << 16);
        cv.u[3] = (b.z & 0xffffu) | (b.w << 16);
        a0 = __builtin_amdgcn_mfma_f32_16x16x32_bf16(cv.fv, wfr[0][4 + j], a0, 0, 0, 0);
        a1 = __builtin_amdgcn_mfma_f32_16x16x32_bf16(cv.fv, wfr[1][4 + j], a1, 0, 0, 0);
        a2 = __builtin_amdgcn_mfma_f32_16x16x32_bf16(cv.fv, wfr[2][4 + j], a2, 0, 0, 0);
        a3 = __builtin_amdgcn_mfma_f32_16x16x32_bf16(cv.fv, wfr[3][4 + j], a3, 0, 0, 0);
      }
      bad = 0;
#pragma unroll
      for (int q = 0; q < 8; ++q)
        bad |= (v[q].x ^ pat) | (v[q].y ^ pat) | (v[q].z ^ pat) | (v[q].w ^ pat);
    } while (!__all((int)((bad & 0xffff0000u) == 0)));

    // ---- cross-wave K reduction via LDS (one barrier per step, parity-double-buffered)
    // C/D layout: col = l15, row = quad*4 + i
#pragma unroll
    for (int i = 0; i < 4; ++i) {
      f32x4 pv = { a0[i], a1[i], a2[i], a3[i] };
      *(f32x4*)&Gp[par][wave][quad * 4 + i][l15 * 4] = pv;
    }
    __syncthreads();

    f32x4 s = *(const f32x4*)&Gp[par][0][erow][ecol * 4];
    s += *(const f32x4*)&Gp[par][1][erow][ecol * 4];
    s += *(const f32x4*)&Gp[par][2][erow][ecol * 4];
    s += *(const f32x4*)&Gp[par][3][erow][ecol * 4];

    // ---- LSTM cell (fp32), per-thread c state
    float fg = sigmoid_fast(s[0] + bias_f);
    float ig = sigmoid_fast(s[1] + bias_i);
    float gg = tanh_fast(s[2] + bias_g);
    float og = sigmoid_fast(s[3] + bias_o);
    c_state = fg * c_state + ig * gg;
    h = og * tanh_fast(c_state);

    // ---- publish: tagged dword payload, then per-wave counter bump (no drain —
    //      tags carry correctness; counter is a cheap readiness hint)
    union { bf16_t b; unsigned short u; } cvt;
    cvt.b = (bf16_t)h;
    uint32_t pk = ((uint32_t)(t + 1) << 16) | (uint32_t)cvt.u;
    store_b32_cc(hexp + ((size_t)((par * 4 + bg)) << 13) + pof, pk);
    if (lane == 0)
      __hip_atomic_fetch_add(&flgc[bg * T_STEPS + t], 1u,
                             __ATOMIC_RELAXED, __HIP_MEMORY_SCOPE_AGENT);

    // ---- out store (off critical path)
    out[((size_t)t * B_SZ + brow) * H_SZ + hcol] = h;
  }

  out[out_hx + (size_t)brow * H_SZ + hcol] = h;
  out[out_hx + (size_t)(B_SZ * H_SZ) + (size_t)brow * H_SZ + hcol] = c_state;
}

extern "C" void kernel_launch(void* const* d_in, const int* in_sizes, int n_in,
                              void* d_out, int out_size, void* d_ws, size_t ws_size,
                              hipStream_t stream) {
  const float* x   = (const float*)d_in[0];
  const float* Wf  = (const float*)d_in[1];
  const float* bfv = (const float*)d_in[2];
  const float* Wi  = (const float*)d_in[3];
  const float* biv = (const float*)d_in[4];
  const float* Wg  = (const float*)d_in[5];
  const float* bgv = (const float*)d_in[6];
  const float* Wo  = (const float*)d_in[7];
  const float* bov = (const float*)d_in[8];
  float* out = (float*)d_out;

  char* ws = (char*)d_ws;
  bf16_t* xbf    = (bf16_t*)(ws + XBF_OFF);
  bf16_t* wbf    = (bf16_t*)(ws + WBF_OFF);
  float*  ball   = (float*)(ws + BALL_OFF);
  uint32_t* hexp = (uint32_t*)(ws + HEXP_OFF);
  uint32_t* flgc = (uint32_t*)(ws + FLGC_OFF);

  prep_x<<<dim3(2048), dim3(256), 0, stream>>>(x, xbf);
  prep_rest<<<dim3(1024), dim3(256), 0, stream>>>(Wf, Wi, Wg, Wo, bfv, biv, bgv, bov,
                                                  wbf, ball, hexp, flgc);
  qlstm_main<<<dim3(NB * NC), dim3(256), 0, stream>>>(xbf, wbf, ball, hexp, flgc, out);
}

// Round 4
// 1859.691 us; speedup vs baseline: 1.0383x; 1.0383x over previous
//
#include <hip/hip_runtime.h>
#include <hip/hip_bf16.h>
#include <stdint.h>

typedef __bf16 bf16_t;
typedef __bf16 bf16x8 __attribute__((ext_vector_type(8)));
typedef __bf16 bf16x4_t __attribute__((ext_vector_type(4)));
typedef float f32x4 __attribute__((ext_vector_type(4)));
typedef uint32_t u32x4 __attribute__((ext_vector_type(4)));

#define T_STEPS 512
#define B_SZ 64
#define I_SZ 512
#define H_SZ 512
#define NB 4            // batch groups (16 rows each)
#define BS 16
#define NC 32           // column-group WGs per batch group (16 h-cols each)
#define CS 16

// ws layout (bytes)
#define XBF_OFF   0ull                     // 32 MB: x bf16, consumer-fragment order
#define WBF_OFF   33554432ull              // 4 MB: W_all bf16 row-major [2048][1024]
#define BALL_OFF  (WBF_OFF + 4194304ull)   // 8 KB: b_all f32
#define HEXP_OFF  (BALL_OFF + 8192ull)     // 256 KB: packed h exchange
// HEXP: [par 2][bg 4][wh 2][kt 8][lane 64][j 8] dwords, each = (tag<<16)|bf16(h)
#define FLG_OFF   (HEXP_OFF + 262144ull)   // 512 B: per-(bg,ic) monotone step flags

__device__ __forceinline__ float sigmoid_fast(float x) {
  return 1.f / (1.f + __expf(-x));
}
__device__ __forceinline__ float tanh_fast(float x) {
  float xc = fminf(fmaxf(x, -10.f), 10.f);
  float e = __expf(2.f * xc);
  return (e - 1.f) / (e + 1.f);
}

// ---- device-coherent (L1+L2 bypass -> Infinity Cache) accessors ----
__device__ __forceinline__ u32x4 load_b128_cc(const void* addr) {
  u32x4 v;
  asm volatile("global_load_dwordx4 %0, %1, off sc0 sc1"
               : "=v"(v) : "v"(addr) : "memory");
  return v;
}
__device__ __forceinline__ void store_b128_cc(void* addr, u32x4 v) {
  asm volatile("global_store_dwordx4 %0, %1, off sc0 sc1"
               :: "v"(addr), "v"(v) : "memory");
}
__device__ __forceinline__ void wait_vm0() {
  asm volatile("s_waitcnt vmcnt(0)" ::: "memory");
}

// ---------- prep: cast x to bf16 in consumer-fragment order ----------
// chunk c (8 bf16): c = t*4096 + bg*1024 + w*512 + kt*64 + lane
// source: row = bg*16 + (lane&15), col = w*256 + kt*32 + (lane>>4)*8
__global__ void prep_x(const float* __restrict__ x, bf16_t* __restrict__ xbf) {
  const int nch = (T_STEPS * B_SZ * I_SZ) / 8;   // 2,097,152
  int c = blockIdx.x * blockDim.x + threadIdx.x;
  int stride = gridDim.x * blockDim.x;
  for (; c < nch; c += stride) {
    int lane = c & 63;
    int kt = (c >> 6) & 7;
    int w  = (c >> 9) & 1;
    int bg = (c >> 10) & 3;
    int t  = c >> 12;
    int r = lane & 15, quad = lane >> 4;
    const float* src = x + ((size_t)t * B_SZ + bg * BS + r) * I_SZ + w * 256 + kt * 32 + quad * 8;
    float4 lo = *(const float4*)src;
    float4 hi = *(const float4*)(src + 4);
    bf16x8 o = { (bf16_t)lo.x, (bf16_t)lo.y, (bf16_t)lo.z, (bf16_t)lo.w,
                 (bf16_t)hi.x, (bf16_t)hi.y, (bf16_t)hi.z, (bf16_t)hi.w };
    *(bf16x8*)(xbf + (size_t)c * 8) = o;
  }
}

// ---------- prep: W_all bf16, b_all f32, zero packed h-exchange + flags ----------
__global__ void prep_rest(const float* __restrict__ wf, const float* __restrict__ wi,
                          const float* __restrict__ wgm, const float* __restrict__ wo,
                          const float* __restrict__ bfv, const float* __restrict__ biv,
                          const float* __restrict__ bgv, const float* __restrict__ bov,
                          bf16_t* __restrict__ wbf, float* __restrict__ ball,
                          uint32_t* __restrict__ hexp, uint32_t* __restrict__ flg) {
  int gtid = blockIdx.x * blockDim.x + threadIdx.x;
  int stride = gridDim.x * blockDim.x;
  const int WCH = (2048 * 1024) / 4;  // 524288 float4 chunks
  for (int i = gtid; i < WCH; i += stride) {
    int r = i >> 8;               // W_all row (0..2047)
    int c = (i & 255) << 2;       // col base
    int g = r >> 9, sr = r & 511;
    const float* src = (g == 0) ? wf : (g == 1) ? wi : (g == 2) ? wgm : wo;
    float4 v = *(const float4*)(src + (size_t)sr * 1024 + c);
    bf16x4_t o = { (bf16_t)v.x, (bf16_t)v.y, (bf16_t)v.z, (bf16_t)v.w };
    *(bf16x4_t*)(wbf + (size_t)r * 1024 + c) = o;
  }
  for (int i = gtid; i < 2048; i += stride) {
    int g = i >> 9;
    const float* src = (g == 0) ? bfv : (g == 1) ? biv : (g == 2) ? bgv : bov;
    ball[i] = src[i & 511];
  }
  for (int i = gtid; i < 65536; i += stride) hexp[i] = 0;   // tag 0 == "h(-1)=0 ready"
  for (int i = gtid; i < NB * NC; i += stride) flg[i] = 0;  // monotone step flags
}

// ---------- main recurrent kernel ----------
// 128 WGs; 4-way symmetric K-split (each wave: 128 x-dims + 128 h-dims);
// per-WG monotone flag hints (no RMW, 1-line spin) + tag-validated bulk load;
// packed producer stores (LDS gather -> 64 dwordx4 per WG).
__global__ __launch_bounds__(256, 1) void qlstm_main(
    const bf16_t* __restrict__ xbf, const bf16_t* __restrict__ wbf,
    const float* __restrict__ ball, uint32_t* __restrict__ hexp,
    uint32_t* __restrict__ flg, float* __restrict__ out) {
  const int wg = blockIdx.x;
  const int bg = wg >> 5;      // batch group 0..3
  const int ic = wg & 31;      // column group 0..31
  const int tid = threadIdx.x;
  const int wave = tid >> 6;   // K-quarter owner (x[128w..] and h[128w..])
  const int lane = tid & 63;
  const int l15 = lane & 15;
  const int quad = lane >> 4;
  const int kq = wave * 4;     // base K-tile (of 32) within each 512-half

  // partial-sum exchange: [par][wave][row 16][col 64(+4 pad)]
  __shared__ __align__(16) float Gp[2][4][16][68];
  // packed h staging for coalesced producer stores
  __shared__ __align__(16) uint32_t Hs[16][16];

  // Register-resident B fragments: W_all row = g*512 + ic*16 + l15
  bf16x8 wfr[4][8];
#pragma unroll
  for (int g = 0; g < 4; ++g) {
    const bf16_t* wp = wbf + ((size_t)(g * 512 + ic * CS + l15)) * 1024 + quad * 8;
#pragma unroll
    for (int j = 0; j < 4; ++j) {
      wfr[g][j]     = *(const bf16x8*)(wp + (kq + j) * 32);
      wfr[g][4 + j] = *(const bf16x8*)(wp + 512 + (kq + j) * 32);
    }
  }

  // per-j offset (x: bf16 elems; hexp: dwords): both are [wh][kt][lane][8]
  int off[4];
#pragma unroll
  for (int j = 0; j < 4; ++j)
    off[j] = (((kq + j) >> 3) << 12) + (((kq + j) & 7) << 9) + lane * 8;

  const int erow = tid >> 4;
  const int ecol = tid & 15;
  const float bias_f = ball[0 * 512 + ic * CS + ecol];
  const float bias_i = ball[1 * 512 + ic * CS + ecol];
  const float bias_g = ball[2 * 512 + ic * CS + ecol];
  const float bias_o = ball[3 * 512 + ic * CS + ecol];

  const int brow = bg * BS + erow;
  const int hcol = ic * CS + ecol;

  // producer packed-store geometry (wave 0 only): lane -> (row, col-quad)
  const int per = lane >> 2;        // 0..15
  const int pq  = lane & 3;         // 0..3
  const int doff = ((ic >> 4) << 12) + (((ic >> 1) & 7) << 9) +
                   ((((ic * 2 + (pq >> 1)) & 3) * 16 + per) << 3) + ((pq & 1) << 2);

  // consumer flag addr: wave w depends exactly on producers ic in [8w, 8w+8)
  const uint32_t* fp = flg + bg * 32 + wave * 8 + (lane & 7);

  float c_state = 0.f, h = 0.f;
  const size_t out_hx = (size_t)T_STEPS * B_SZ * H_SZ;

  const bf16_t* xwb = xbf + ((size_t)bg << 13);   // + t<<15 + off[j]

#pragma unroll 1
  for (int t = 0; t < T_STEPS; ++t) {
    const int par = t & 1;
    const uint32_t tagv = (uint32_t)t;

    // ---- readiness pre-probe issued early (latency hides under x phase)
    uint32_t fv = __hip_atomic_load(fp, __ATOMIC_RELAXED, __HIP_MEMORY_SCOPE_AGENT);

    // ---- x K-quarter: fragment loads + MFMA (off critical path)
    f32x4 x0 = {0, 0, 0, 0}, x1 = {0, 0, 0, 0}, x2 = {0, 0, 0, 0}, x3 = {0, 0, 0, 0};
    {
      const bf16_t* xp = xwb + ((size_t)t << 15);
      bf16x8 fx0 = *(const bf16x8*)(xp + off[0]);
      bf16x8 fx1 = *(const bf16x8*)(xp + off[1]);
      bf16x8 fx2 = *(const bf16x8*)(xp + off[2]);
      bf16x8 fx3 = *(const bf16x8*)(xp + off[3]);
      x0 = __builtin_amdgcn_mfma_f32_16x16x32_bf16(fx0, wfr[0][0], x0, 0, 0, 0);
      x1 = __builtin_amdgcn_mfma_f32_16x16x32_bf16(fx0, wfr[1][0], x1, 0, 0, 0);
      x2 = __builtin_amdgcn_mfma_f32_16x16x32_bf16(fx0, wfr[2][0], x2, 0, 0, 0);
      x3 = __builtin_amdgcn_mfma_f32_16x16x32_bf16(fx0, wfr[3][0], x3, 0, 0, 0);
      x0 = __builtin_amdgcn_mfma_f32_16x16x32_bf16(fx1, wfr[0][1], x0, 0, 0, 0);
      x1 = __builtin_amdgcn_mfma_f32_16x16x32_bf16(fx1, wfr[1][1], x1, 0, 0, 0);
      x2 = __builtin_amdgcn_mfma_f32_16x16x32_bf16(fx1, wfr[2][1], x2, 0, 0, 0);
      x3 = __builtin_amdgcn_mfma_f32_16x16x32_bf16(fx1, wfr[3][1], x3, 0, 0, 0);
      x0 = __builtin_amdgcn_mfma_f32_16x16x32_bf16(fx2, wfr[0][2], x0, 0, 0, 0);
      x1 = __builtin_amdgcn_mfma_f32_16x16x32_bf16(fx2, wfr[1][2], x1, 0, 0, 0);
      x2 = __builtin_amdgcn_mfma_f32_16x16x32_bf16(fx2, wfr[2][2], x2, 0, 0, 0);
      x3 = __builtin_amdgcn_mfma_f32_16x16x32_bf16(fx2, wfr[3][2], x3, 0, 0, 0);
      x0 = __builtin_amdgcn_mfma_f32_16x16x32_bf16(fx3, wfr[0][3], x0, 0, 0, 0);
      x1 = __builtin_amdgcn_mfma_f32_16x16x32_bf16(fx3, wfr[1][3], x1, 0, 0, 0);
      x2 = __builtin_amdgcn_mfma_f32_16x16x32_bf16(fx3, wfr[2][3], x2, 0, 0, 0);
      x3 = __builtin_amdgcn_mfma_f32_16x16x32_bf16(fx3, wfr[3][3], x3, 0, 0, 0);
    }

    // ---- gate on the 8 relevant producer flags (one line, broadcast read)
    if (!__all((int)(fv >= tagv))) {
      do {
        __builtin_amdgcn_s_sleep(1);
        fv = __hip_atomic_load(fp, __ATOMIC_RELAXED, __HIP_MEMORY_SCOPE_AGENT);
      } while (!__all((int)(fv >= tagv)));
    }

    // ---- bulk load h quarter; MFMA speculatively; tag-validate under MFMA latency
    const uint32_t* hb = hexp + ((size_t)(((par ^ 1) * 4 + bg)) << 13);
    const uint32_t pat = tagv << 16;
    f32x4 a0, a1, a2, a3;
    for (;;) {
      u32x4 v[8];
#pragma unroll
      for (int j = 0; j < 4; ++j) {
        v[2 * j]     = load_b128_cc(hb + off[j]);
        v[2 * j + 1] = load_b128_cc(hb + off[j] + 4);
      }
      wait_vm0();
      a0 = x0; a1 = x1; a2 = x2; a3 = x3;
#pragma unroll
      for (int j = 0; j < 4; ++j) {
        u32x4 a = v[2 * j], b = v[2 * j + 1];
        union { uint32_t u[4]; bf16x8 fv2; } cv;
        cv.u[0] = (a.x & 0xffffu) | (a.y << 16);
        cv.u[1] = (a.z & 0xffffu) | (a.w << 16);
        cv.u[2] = (b.x & 0xffffu) | (b.y << 16);
        cv.u[3] = (b.z & 0xffffu) | (b.w << 16);
        a0 = __builtin_amdgcn_mfma_f32_16x16x32_bf16(cv.fv2, wfr[0][4 + j], a0, 0, 0, 0);
        a1 = __builtin_amdgcn_mfma_f32_16x16x32_bf16(cv.fv2, wfr[1][4 + j], a1, 0, 0, 0);
        a2 = __builtin_amdgcn_mfma_f32_16x16x32_bf16(cv.fv2, wfr[2][4 + j], a2, 0, 0, 0);
        a3 = __builtin_amdgcn_mfma_f32_16x16x32_bf16(cv.fv2, wfr[3][4 + j], a3, 0, 0, 0);
      }
      uint32_t bad = 0;
#pragma unroll
      for (int q = 0; q < 8; ++q)
        bad |= (v[q].x ^ pat) | (v[q].y ^ pat) | (v[q].z ^ pat) | (v[q].w ^ pat);
      if (__all((int)((bad & 0xffff0000u) == 0))) break;
      __builtin_amdgcn_s_sleep(1);
    }

    // ---- cross-wave K reduction via LDS (parity-double-buffered)
    // C/D layout: col = l15, row = quad*4 + i
#pragma unroll
    for (int i = 0; i < 4; ++i) {
      f32x4 pv = { a0[i], a1[i], a2[i], a3[i] };
      *(f32x4*)&Gp[par][wave][quad * 4 + i][l15 * 4] = pv;
    }
    __syncthreads();  // S2: Gp ready

    f32x4 s = *(const f32x4*)&Gp[par][0][erow][ecol * 4];
    s += *(const f32x4*)&Gp[par][1][erow][ecol * 4];
    s += *(const f32x4*)&Gp[par][2][erow][ecol * 4];
    s += *(const f32x4*)&Gp[par][3][erow][ecol * 4];

    // ---- LSTM cell (fp32), per-thread c state
    float fg = sigmoid_fast(s[0] + bias_f);
    float ig = sigmoid_fast(s[1] + bias_i);
    float gg = tanh_fast(s[2] + bias_g);
    float og = sigmoid_fast(s[3] + bias_o);
    c_state = fg * c_state + ig * gg;
    h = og * tanh_fast(c_state);

    // ---- publish: pack (tag|h) via LDS, wave 0 issues 64 dwordx4 + flag
    union { bf16_t b; unsigned short u; } cvt;
    cvt.b = (bf16_t)h;
    Hs[erow][ecol] = ((uint32_t)(t + 1) << 16) | (uint32_t)cvt.u;
    __syncthreads();  // S3: Hs complete
    if (wave == 0) {
      u32x4 hv = *(const u32x4*)&Hs[per][pq * 4];
      store_b128_cc(hexp + (((size_t)(par * 4 + bg)) << 13) + doff, hv);
      if (lane == 0)
        __hip_atomic_store(&flg[bg * 32 + ic], (uint32_t)(t + 1),
                           __ATOMIC_RELAXED, __HIP_MEMORY_SCOPE_AGENT);
    }

    // ---- out store (off critical path, naturally coalesced)
    out[((size_t)t * B_SZ + brow) * H_SZ + hcol] = h;
  }

  out[out_hx + (size_t)brow * H_SZ + hcol] = h;
  out[out_hx + (size_t)(B_SZ * H_SZ) + (size_t)brow * H_SZ + hcol] = c_state;
}

extern "C" void kernel_launch(void* const* d_in, const int* in_sizes, int n_in,
                              void* d_out, int out_size, void* d_ws, size_t ws_size,
                              hipStream_t stream) {
  const float* x   = (const float*)d_in[0];
  const float* Wf  = (const float*)d_in[1];
  const float* bfv = (const float*)d_in[2];
  const float* Wi  = (const float*)d_in[3];
  const float* biv = (const float*)d_in[4];
  const float* Wg  = (const float*)d_in[5];
  const float* bgv = (const float*)d_in[6];
  const float* Wo  = (const float*)d_in[7];
  const float* bov = (const float*)d_in[8];
  float* out = (float*)d_out;

  char* ws = (char*)d_ws;
  bf16_t* xbf    = (bf16_t*)(ws + XBF_OFF);
  bf16_t* wbf    = (bf16_t*)(ws + WBF_OFF);
  float*  ball   = (float*)(ws + BALL_OFF);
  uint32_t* hexp = (uint32_t*)(ws + HEXP_OFF);
  uint32_t* flg  = (uint32_t*)(ws + FLG_OFF);

  prep_x<<<dim3(2048), dim3(256), 0, stream>>>(x, xbf);
  prep_rest<<<dim3(1024), dim3(256), 0, stream>>>(Wf, Wi, Wg, Wo, bfv, biv, bgv, bov,
                                                  wbf, ball, hexp, flg);
  qlstm_main<<<dim3(NB * NC), dim3(256), 0, stream>>>(xbf, wbf, ball, hexp, flg, out);
}

// Round 7
// 1175.059 us; speedup vs baseline: 1.6433x; 1.5826x over previous
//
#include <hip/hip_runtime.h>
#include <hip/hip_bf16.h>
#include <stdint.h>

typedef __bf16 bf16_t;
typedef __bf16 bf16x8 __attribute__((ext_vector_type(8)));
typedef __bf16 bf16x4_t __attribute__((ext_vector_type(4)));
typedef float f32x4 __attribute__((ext_vector_type(4)));
typedef uint32_t u32x4 __attribute__((ext_vector_type(4)));

#define T_STEPS 512
#define B_SZ 64
#define I_SZ 512
#define H_SZ 512
#define NB 4            // batch groups (16 rows each)
#define BS 16
#define NC 32           // column-group WGs per batch group (16 h-cols each)
#define CS 16

// ws layout (bytes)
#define XBF_OFF   0ull                     // 32 MB: x bf16, consumer-fragment order
#define WBF_OFF   33554432ull              // 4 MB: W_all bf16 row-major [2048][1024]
#define BALL_OFF  (WBF_OFF + 4194304ull)   // 8 KB: b_all f32
#define HEXP_OFF  (BALL_OFF + 8192ull)     // 256 KB: packed h exchange
// HEXP: [par 2][bg 4][wh 2][kt 8][lane 64][j 8] dwords, each = (tag<<16)|bf16(h)

__device__ __forceinline__ float sigmoid_fast(float x) {
  return 1.f / (1.f + __expf(-x));
}
__device__ __forceinline__ float tanh_fast(float x) {
  float xc = fminf(fmaxf(x, -10.f), 10.f);
  float e = __expf(2.f * xc);
  return (e - 1.f) / (e + 1.f);
}

// ---- device-coherent (L1+L2 bypass -> Infinity Cache) accessors (R1-proven) ----
__device__ __forceinline__ u32x4 load_b128_cc(const void* addr) {
  u32x4 v;
  asm volatile("global_load_dwordx4 %0, %1, off sc0 sc1"
               : "=v"(v) : "v"(addr) : "memory");
  return v;
}
__device__ __forceinline__ void store_b32_cc(void* addr, uint32_t v) {
  asm volatile("global_store_dword %0, %1, off sc0 sc1"
               :: "v"(addr), "v"(v) : "memory");
}
__device__ __forceinline__ void wait_vm0() {
  asm volatile("s_waitcnt vmcnt(0)" ::: "memory");
}

// ---------- prep: cast x to bf16 in consumer-fragment order ----------
// chunk c (8 bf16): c = t*4096 + bg*1024 + w*512 + kt*64 + lane
// source: row = bg*16 + (lane&15), col = w*256 + kt*32 + (lane>>4)*8
__global__ void prep_x(const float* __restrict__ x, bf16_t* __restrict__ xbf) {
  const int nch = (T_STEPS * B_SZ * I_SZ) / 8;   // 2,097,152
  int c = blockIdx.x * blockDim.x + threadIdx.x;
  int stride = gridDim.x * blockDim.x;
  for (; c < nch; c += stride) {
    int lane = c & 63;
    int kt = (c >> 6) & 7;
    int w  = (c >> 9) & 1;
    int bg = (c >> 10) & 3;
    int t  = c >> 12;
    int r = lane & 15, quad = lane >> 4;
    const float* src = x + ((size_t)t * B_SZ + bg * BS + r) * I_SZ + w * 256 + kt * 32 + quad * 8;
    float4 lo = *(const float4*)src;
    float4 hi = *(const float4*)(src + 4);
    bf16x8 o = { (bf16_t)lo.x, (bf16_t)lo.y, (bf16_t)lo.z, (bf16_t)lo.w,
                 (bf16_t)hi.x, (bf16_t)hi.y, (bf16_t)hi.z, (bf16_t)hi.w };
    *(bf16x8*)(xbf + (size_t)c * 8) = o;
  }
}

// ---------- prep: W_all bf16, b_all f32, zero packed h-exchange ----------
__global__ void prep_rest(const float* __restrict__ wf, const float* __restrict__ wi,
                          const float* __restrict__ wgm, const float* __restrict__ wo,
                          const float* __restrict__ bfv, const float* __restrict__ biv,
                          const float* __restrict__ bgv, const float* __restrict__ bov,
                          bf16_t* __restrict__ wbf, float* __restrict__ ball,
                          uint32_t* __restrict__ hexp) {
  int gtid = blockIdx.x * blockDim.x + threadIdx.x;
  int stride = gridDim.x * blockDim.x;
  const int WCH = (2048 * 1024) / 4;  // 524288 float4 chunks
  for (int i = gtid; i < WCH; i += stride) {
    int r = i >> 8;               // W_all row (0..2047)
    int c = (i & 255) << 2;       // col base
    int g = r >> 9, sr = r & 511;
    const float* src = (g == 0) ? wf : (g == 1) ? wi : (g == 2) ? wgm : wo;
    float4 v = *(const float4*)(src + (size_t)sr * 1024 + c);
    bf16x4_t o = { (bf16_t)v.x, (bf16_t)v.y, (bf16_t)v.z, (bf16_t)v.w };
    *(bf16x4_t*)(wbf + (size_t)r * 1024 + c) = o;
  }
  for (int i = gtid; i < 2048; i += stride) {
    int g = i >> 9;
    const float* src = (g == 0) ? bfv : (g == 1) ? biv : (g == 2) ? bgv : bov;
    ball[i] = src[i & 511];
  }
  for (int i = gtid; i < 65536; i += stride) hexp[i] = 0;  // tag 0 == "h(-1)=0 ready"
}

// ---------- main recurrent kernel ----------
// 128 WGs; 4-way symmetric K-split (each wave: 128 x-dims + 128 h-dims);
// R1-proven sync: tag-in-payload, poll-is-fetch, parity double-buffer.
__global__ __launch_bounds__(256, 1) void qlstm_main(
    const bf16_t* __restrict__ xbf, const bf16_t* __restrict__ wbf,
    const float* __restrict__ ball, uint32_t* __restrict__ hexp,
    float* __restrict__ out) {
  const int wg = blockIdx.x;
  const int bg = wg >> 5;      // batch group 0..3
  const int ic = wg & 31;      // column group 0..31
  const int tid = threadIdx.x;
  const int wave = tid >> 6;   // K-quarter owner (x[128w..] and h[128w..])
  const int lane = tid & 63;
  const int l15 = lane & 15;
  const int quad = lane >> 4;
  const int kq = wave * 4;     // base K-tile (of 32) within each 512-half

  // partial-sum exchange: [par][wave][row 16][col 64(+4 pad)]
  __shared__ __align__(16) float Gp[2][4][16][68];

  // Register-resident B fragments: W_all row = g*512 + ic*16 + l15
  // j<4: x quarter, col = (kq+j)*32 + quad*8 ; j>=4: h quarter, col = 512 + (kq+j-4)*32 + quad*8
  bf16x8 wfr[4][8];
#pragma unroll
  for (int g = 0; g < 4; ++g) {
    const bf16_t* wp = wbf + ((size_t)(g * 512 + ic * CS + l15)) * 1024 + quad * 8;
#pragma unroll
    for (int j = 0; j < 4; ++j) {
      wfr[g][j]     = *(const bf16x8*)(wp + (kq + j) * 32);
      wfr[g][4 + j] = *(const bf16x8*)(wp + 512 + (kq + j) * 32);
    }
  }

  // per-j offset (x: bf16 elems; hexp: dwords): both are [wh][kt][lane][8]
  int off[4];
#pragma unroll
  for (int j = 0; j < 4; ++j)
    off[j] = (((kq + j) >> 3) << 12) + (((kq + j) & 7) << 9) + lane * 8;

  const int erow = tid >> 4;
  const int ecol = tid & 15;
  const float bias_f = ball[0 * 512 + ic * CS + ecol];
  const float bias_i = ball[1 * 512 + ic * CS + ecol];
  const float bias_g = ball[2 * 512 + ic * CS + ecol];
  const float bias_o = ball[3 * 512 + ic * CS + ecol];

  const int brow = bg * BS + erow;
  const int hcol = ic * CS + ecol;

  // producer dest: fragment position of (erow, hcol) in consumer layout
  const int wh = hcol >> 8;
  const int kp = hcol & 255;
  const int pof = wh * 4096 + ((kp >> 5) << 9) + ((((kp >> 3) & 3) * 16 + erow) << 3) + (kp & 7);

  float c_state = 0.f, h = 0.f;
  const size_t out_hx = (size_t)T_STEPS * B_SZ * H_SZ;

  const bf16_t* xwb = xbf + ((size_t)bg << 13);   // + t<<15 + off[j]

#pragma unroll 1
  for (int t = 0; t < T_STEPS; ++t) {
    const int par = t & 1;
    const uint32_t pat = (uint32_t)t << 16;

    // ---- x K-quarter: fragment loads + MFMA (hidden from critical path)
    f32x4 x0 = {0, 0, 0, 0}, x1 = {0, 0, 0, 0}, x2 = {0, 0, 0, 0}, x3 = {0, 0, 0, 0};
    {
      const bf16_t* xp = xwb + ((size_t)t << 15);
      bf16x8 fx0 = *(const bf16x8*)(xp + off[0]);
      bf16x8 fx1 = *(const bf16x8*)(xp + off[1]);
      bf16x8 fx2 = *(const bf16x8*)(xp + off[2]);
      bf16x8 fx3 = *(const bf16x8*)(xp + off[3]);
      x0 = __builtin_amdgcn_mfma_f32_16x16x32_bf16(fx0, wfr[0][0], x0, 0, 0, 0);
      x1 = __builtin_amdgcn_mfma_f32_16x16x32_bf16(fx0, wfr[1][0], x1, 0, 0, 0);
      x2 = __builtin_amdgcn_mfma_f32_16x16x32_bf16(fx0, wfr[2][0], x2, 0, 0, 0);
      x3 = __builtin_amdgcn_mfma_f32_16x16x32_bf16(fx0, wfr[3][0], x3, 0, 0, 0);
      x0 = __builtin_amdgcn_mfma_f32_16x16x32_bf16(fx1, wfr[0][1], x0, 0, 0, 0);
      x1 = __builtin_amdgcn_mfma_f32_16x16x32_bf16(fx1, wfr[1][1], x1, 0, 0, 0);
      x2 = __builtin_amdgcn_mfma_f32_16x16x32_bf16(fx1, wfr[2][1], x2, 0, 0, 0);
      x3 = __builtin_amdgcn_mfma_f32_16x16x32_bf16(fx1, wfr[3][1], x3, 0, 0, 0);
      x0 = __builtin_amdgcn_mfma_f32_16x16x32_bf16(fx2, wfr[0][2], x0, 0, 0, 0);
      x1 = __builtin_amdgcn_mfma_f32_16x16x32_bf16(fx2, wfr[1][2], x1, 0, 0, 0);
      x2 = __builtin_amdgcn_mfma_f32_16x16x32_bf16(fx2, wfr[2][2], x2, 0, 0, 0);
      x3 = __builtin_amdgcn_mfma_f32_16x16x32_bf16(fx2, wfr[3][2], x3, 0, 0, 0);
      x0 = __builtin_amdgcn_mfma_f32_16x16x32_bf16(fx3, wfr[0][3], x0, 0, 0, 0);
      x1 = __builtin_amdgcn_mfma_f32_16x16x32_bf16(fx3, wfr[1][3], x1, 0, 0, 0);
      x2 = __builtin_amdgcn_mfma_f32_16x16x32_bf16(fx3, wfr[2][3], x2, 0, 0, 0);
      x3 = __builtin_amdgcn_mfma_f32_16x16x32_bf16(fx3, wfr[3][3], x3, 0, 0, 0);
    }

    // ---- poll-is-fetch on this wave's h quarter (8 b128, tags ride with payload)
    const uint32_t* hb = hexp + ((size_t)(((par ^ 1) * 4 + bg)) << 13);
    u32x4 v[8];
    for (;;) {
#pragma unroll
      for (int j = 0; j < 4; ++j) {
        v[2 * j]     = load_b128_cc(hb + off[j]);
        v[2 * j + 1] = load_b128_cc(hb + off[j] + 4);
      }
      wait_vm0();
      uint32_t bad = 0;
#pragma unroll
      for (int q = 0; q < 8; ++q)
        bad |= (v[q].x ^ pat) | (v[q].y ^ pat) | (v[q].z ^ pat) | (v[q].w ^ pat);
      if (__all((int)((bad & 0xffff0000u) == 0))) break;
      __builtin_amdgcn_s_sleep(1);
    }

    // ---- unpack + h K-quarter MFMA (16 MFMAs post-detect)
    f32x4 a0 = x0, a1 = x1, a2 = x2, a3 = x3;
#pragma unroll
    for (int j = 0; j < 4; ++j) {
      u32x4 a = v[2 * j], b = v[2 * j + 1];
      union { uint32_t u[4]; bf16x8 fv2; } cv;
      cv.u[0] = (a.x & 0xffffu) | (a.y << 16);
      cv.u[1] = (a.z & 0xffffu) | (a.w << 16);
      cv.u[2] = (b.x & 0xffffu) | (b.y << 16);
      cv.u[3] = (b.z & 0xffffu) | (b.w << 16);
      a0 = __builtin_amdgcn_mfma_f32_16x16x32_bf16(cv.fv2, wfr[0][4 + j], a0, 0, 0, 0);
      a1 = __builtin_amdgcn_mfma_f32_16x16x32_bf16(cv.fv2, wfr[1][4 + j], a1, 0, 0, 0);
      a2 = __builtin_amdgcn_mfma_f32_16x16x32_bf16(cv.fv2, wfr[2][4 + j], a2, 0, 0, 0);
      a3 = __builtin_amdgcn_mfma_f32_16x16x32_bf16(cv.fv2, wfr[3][4 + j], a3, 0, 0, 0);
    }

    // ---- cross-wave K reduction via LDS (parity-double-buffered)
    // C/D layout: col = l15, row = quad*4 + i
#pragma unroll
    for (int i = 0; i < 4; ++i) {
      f32x4 pv = { a0[i], a1[i], a2[i], a3[i] };
      *(f32x4*)&Gp[par][wave][quad * 4 + i][l15 * 4] = pv;
    }
    __syncthreads();  // S2: Gp ready

    f32x4 s = *(const f32x4*)&Gp[par][0][erow][ecol * 4];
    s += *(const f32x4*)&Gp[par][1][erow][ecol * 4];
    s += *(const f32x4*)&Gp[par][2][erow][ecol * 4];
    s += *(const f32x4*)&Gp[par][3][erow][ecol * 4];

    // ---- LSTM cell (fp32), per-thread c state
    float fg = sigmoid_fast(s[0] + bias_f);
    float ig = sigmoid_fast(s[1] + bias_i);
    float gg = tanh_fast(s[2] + bias_g);
    float og = sigmoid_fast(s[3] + bias_o);
    c_state = fg * c_state + ig * gg;
    h = og * tanh_fast(c_state);

    // ---- publish: single tagged dword (tag t+1 | bf16 h), no drain, no flag
    union { bf16_t b; unsigned short u; } cvt;
    cvt.b = (bf16_t)h;
    uint32_t pk = ((uint32_t)(t + 1) << 16) | (uint32_t)cvt.u;
    store_b32_cc(hexp + ((size_t)((par * 4 + bg)) << 13) + pof, pk);

    // ---- out store (off critical path, naturally coalesced)
    out[((size_t)t * B_SZ + brow) * H_SZ + hcol] = h;
  }

  out[out_hx + (size_t)brow * H_SZ + hcol] = h;
  out[out_hx + (size_t)(B_SZ * H_SZ) + (size_t)brow * H_SZ + hcol] = c_state;
}

extern "C" void kernel_launch(void* const* d_in, const int* in_sizes, int n_in,
                              void* d_out, int out_size, void* d_ws, size_t ws_size,
                              hipStream_t stream) {
  const float* x   = (const float*)d_in[0];
  const float* Wf  = (const float*)d_in[1];
  const float* bfv = (const float*)d_in[2];
  const float* Wi  = (const float*)d_in[3];
  const float* biv = (const float*)d_in[4];
  const float* Wg  = (const float*)d_in[5];
  const float* bgv = (const float*)d_in[6];
  const float* Wo  = (const float*)d_in[7];
  const float* bov = (const float*)d_in[8];
  float* out = (float*)d_out;

  char* ws = (char*)d_ws;
  bf16_t* xbf    = (bf16_t*)(ws + XBF_OFF);
  bf16_t* wbf    = (bf16_t*)(ws + WBF_OFF);
  float*  ball   = (float*)(ws + BALL_OFF);
  uint32_t* hexp = (uint32_t*)(ws + HEXP_OFF);

  prep_x<<<dim3(2048), dim3(256), 0, stream>>>(x, xbf);
  prep_rest<<<dim3(1024), dim3(256), 0, stream>>>(Wf, Wi, Wg, Wo, bfv, biv, bgv, bov,
                                                  wbf, ball, hexp);
  qlstm_main<<<dim3(NB * NC), dim3(256), 0, stream>>>(xbf, wbf, ball, hexp, out);
}